// Round 1
// baseline (57.541 us; speedup 1.0000x reference)
//
#include <hip/hip_runtime.h>

#define N_TASKS 16
#define LMAX 64
#define LDS_STRIDE 68  // 68%32=4 -> tasks staggered across banks; 272B row keeps 16B alignment

__global__ __launch_bounds__(256) void MultiElementWiseAffine_kernel(
    const float* __restrict__ input,      // [B]
    const int*   __restrict__ task_ids,   // [B]
    const float* __restrict__ offsets,    // [N_TASKS*LMAX]
    const float* __restrict__ disc,       // [N_TASKS*LMAX]
    const int*   __restrict__ lengths,    // [N_TASKS]
    float4*      __restrict__ out,        // [B*16] float4 view of [B][64]
    int total4)                           // B*16
{
    __shared__ alignas(16) float s_off[N_TASKS * LDS_STRIDE];
    __shared__ alignas(16) float s_mdisc[N_TASKS * LDS_STRIDE];

    // Stage tables; fold the validity mask into the discrimination table.
    for (int i = threadIdx.x; i < N_TASKS * LMAX; i += blockDim.x) {
        int t = i >> 6;          // task
        int k = i & (LMAX - 1);  // threshold index
        s_off[t * LDS_STRIDE + k]   = offsets[i];
        s_mdisc[t * LDS_STRIDE + k] = (k < lengths[t]) ? disc[i] : 0.0f;
    }
    __syncthreads();

    const int stride = gridDim.x * blockDim.x;
    for (int g = blockIdx.x * blockDim.x + threadIdx.x; g < total4; g += stride) {
        int row = g >> 4;   // which input row
        int k4  = g & 15;   // which float4 within the row
        int t   = task_ids[row];
        float x = input[row];
        const float* o = &s_off[t * LDS_STRIDE + (k4 << 2)];
        const float* m = &s_mdisc[t * LDS_STRIDE + (k4 << 2)];
        float4 r;
        r.x = m[0] * (x + o[0]);
        r.y = m[1] * (x + o[1]);
        r.z = m[2] * (x + o[2]);
        r.w = m[3] * (x + o[3]);
        out[g] = r;
    }
}

extern "C" void kernel_launch(void* const* d_in, const int* in_sizes, int n_in,
                              void* d_out, int out_size, void* d_ws, size_t ws_size,
                              hipStream_t stream) {
    const float* input    = (const float*)d_in[0];
    const int*   task_ids = (const int*)d_in[1];
    const float* offsets  = (const float*)d_in[2];
    const float* disc     = (const float*)d_in[3];
    const int*   lengths  = (const int*)d_in[4];
    float4*      out      = (float4*)d_out;

    int total4 = out_size / 4;           // B * 16
    int block  = 256;
    int grid   = 2048;                   // grid-stride; 2048*256 threads, 32 iters each

    MultiElementWiseAffine_kernel<<<grid, block, 0, stream>>>(
        input, task_ids, offsets, disc, lengths, out, total4);
}